// Round 1
// 155.009 us; speedup vs baseline: 1.0394x; 1.0394x over previous
//
#include <hip/hip_runtime.h>
#include <hip/hip_bf16.h>

typedef __bf16 bf16x8 __attribute__((ext_vector_type(8)));
typedef __bf16 bf16x4v __attribute__((ext_vector_type(4)));
typedef float  f32x4  __attribute__((ext_vector_type(4)));

#define T_TOK   2304
#define HID     1280
#define QKV_N   3840
#define NH      16
#define HD      80
#define NWIN    36

// ---------------------------------------------------------------------------
// async global->LDS 16B copy (wave-uniform LDS base + lane*16 semantics)
// ---------------------------------------------------------------------------
__device__ inline void async_copy16(const __bf16* g, __bf16* l) {
    __builtin_amdgcn_global_load_lds(
        (const __attribute__((address_space(1))) unsigned int*)g,
        (__attribute__((address_space(3))) unsigned int*)l, 16, 0, 0);
}

// ---------------------------------------------------------------------------
// prep: range0 converts x fp32->bf16; range1/2 transpose-convert Wqkv / Wo
// to B^T bf16 layout. Single launch, 3-range 1D grid.
// ---------------------------------------------------------------------------
#define NB_CONV 1440   // 2304*1280 / (256*8)
#define NB_WQKV 1200   // (1280/64) * (3840/64)
#define NB_WO    400   // (1280/64) * (1280/64)

__global__ __launch_bounds__(256) void prep_kernel(
    const float* __restrict__ x,    __bf16* __restrict__ Xb,
    const float* __restrict__ Wqkv, __bf16* __restrict__ Wqkv_t,
    const float* __restrict__ Wo,   __bf16* __restrict__ Wo_t)
{
    __shared__ float t[64][65];
    int b = blockIdx.x;
    const int tid = threadIdx.x;

    if (b < NB_CONV) {
        const int i = (b * 256 + tid) * 8;
        const float4* p = (const float4*)(x + i);
        float4 a0 = p[0], a1 = p[1];
        bf16x8 o;
        o[0] = (__bf16)a0.x; o[1] = (__bf16)a0.y; o[2] = (__bf16)a0.z; o[3] = (__bf16)a0.w;
        o[4] = (__bf16)a1.x; o[5] = (__bf16)a1.y; o[6] = (__bf16)a1.z; o[7] = (__bf16)a1.w;
        *(bf16x8*)(Xb + i) = o;
        return;
    }

    const float* in; __bf16* out; int C, c0, r0;
    const int R = 1280;
    if (b < NB_CONV + NB_WQKV) {
        b -= NB_CONV;
        in = Wqkv; out = Wqkv_t; C = QKV_N;
        c0 = (b % 60) * 64; r0 = (b / 60) * 64;
    } else {
        b -= NB_CONV + NB_WQKV;
        in = Wo; out = Wo_t; C = HID;
        c0 = (b % 20) * 64; r0 = (b / 20) * 64;
    }

    const int lr = tid >> 4;
    const int lc = (tid & 15) * 4;
#pragma unroll
    for (int i = 0; i < 4; ++i) {
        float4 v = *(const float4*)(in + (size_t)(r0 + lr + i * 16) * C + c0 + lc);
        float* d = &t[lr + i * 16][lc];
        d[0] = v.x; d[1] = v.y; d[2] = v.z; d[3] = v.w;
    }
    __syncthreads();
    const int oc  = tid >> 4;
    const int orr = (tid & 15) * 4;
#pragma unroll
    for (int i = 0; i < 4; ++i) {
        const int c = oc + i * 16;
        bf16x4v o;
        o[0] = (__bf16)t[orr + 0][c];
        o[1] = (__bf16)t[orr + 1][c];
        o[2] = (__bf16)t[orr + 2][c];
        o[3] = (__bf16)t[orr + 3][c];
        *(bf16x4v*)(out + (size_t)(c0 + c) * R + r0 + orr) = o;
    }
}

// ---------------------------------------------------------------------------
// 8-phase deep-pipelined GEMM for QKV:  out[2304,3840] = A[2304,1280] @
// Bt[3840,1280]^T + bias.  BM=BN=192, BK=64, 8 waves (2M x 4N, per-wave
// 96x48), grid 20x12 = 240 blocks (94% CU coverage).
//
// Schedule (per iteration = K-tiles e=2i (buf0) and o=2i+1 (buf1)):
//   P1: ldA(0,lo)+ldB01(0) | stage A1,A2(o)      | MMA e:(mlo x n01)
//   P2: ldB2(0)            |                     | MMA e:(mlo x n2)
//   P3: ldA(0,hi)          | stage B0,B1(e+2)    | MMA e:(mhi x n01)
//   P4:                    | stage B2,A0(e+2)    | vmcnt(4) | MMA e:(mhi x n2)
//   P5..P8: same on buf1 / tile o, staging A1,A2(e+2), B0,B1(o+2), B2,A0(o+2)
// Each stage unit = 512 chunks = 1 global_load_lds/thread; a unit is staged
// only after its LDS region is dead (B units die after P2, A units after P3).
// vmcnt is counted (4 = 2 units in flight across the barrier), never 0 in
// the main loop; raw s_barrier (no __syncthreads -> no vmcnt(0) drain).
// LDS XOR swizzle chunk^=(row&7) applied on the read side and inverted on
// the global source address (global_load_lds dest stays linear).
// ---------------------------------------------------------------------------
#define BAR()   asm volatile("s_barrier" ::: "memory")
#define VMC(n)  asm volatile("s_waitcnt vmcnt(" #n ")" ::: "memory")

__global__ __launch_bounds__(512, 2) void gemm192_kernel(
    const __bf16* __restrict__ A,    // [2304,1280]
    const __bf16* __restrict__ Bt,   // [3840,1280]
    const float* __restrict__ bias,  // [3840]
    __bf16* __restrict__ out)        // [2304,3840]
{
    // 2 bufs x (A 192x64 + B 192x64) bf16 = 96 KiB
    __shared__ __align__(16) __bf16 S[49152];

    const int tid  = threadIdx.x;
    const int wave = tid >> 6, lane = tid & 63;
    const int quad = lane >> 4, l16 = lane & 15;
    const int wr = wave >> 2, wn = wave & 3;
    const int m0 = blockIdx.y * 192;
    const int n0 = blockIdx.x * 192;

    // staging: chunk c = chunk0 + tid; row-in-unit = tid>>3; dest col = tid&7;
    // source k-chunk = (tid&7) ^ (row&7)  (inverse swizzle on global addr)
    const int rloc = tid >> 3;
    const int kcol = ((tid & 7) ^ (rloc & 7)) * 8;

    auto stage_unit = [&](const __bf16* g, int grow, int k0, int chunk0) {
        async_copy16(g + (size_t)(grow + rloc) * 1280 + (k0 + kcol),
                     S + (chunk0 + tid) * 8);
    };

    // ds-read swizzled chunk offsets (elements) for ksub 0 / 1
    const int chS0 = ((quad) ^ (l16 & 7)) * 8;
    const int chS1 = ((4 + quad) ^ (l16 & 7)) * 8;

    bf16x8 aF[3][2], bF[3][2];
    f32x4 acc[6][3] = {};

#define LDA(buf, mh)                                                          \
    {                                                                         \
      const __bf16* base_ = S + (buf)*24576 + (wr*96 + (mh)*48 + l16) * 64;   \
      _Pragma("unroll") for (int m_ = 0; m_ < 3; ++m_) {                      \
        aF[m_][0] = *(const bf16x8*)(base_ + m_*1024 + chS0);                 \
        aF[m_][1] = *(const bf16x8*)(base_ + m_*1024 + chS1);                 \
      }                                                                       \
    }
#define LDB01(buf)                                                            \
    {                                                                         \
      const __bf16* base_ = S + (buf)*24576 + 12288 + (wn*48 + l16) * 64;     \
      _Pragma("unroll") for (int n_ = 0; n_ < 2; ++n_) {                      \
        bF[n_][0] = *(const bf16x8*)(base_ + n_*1024 + chS0);                 \
        bF[n_][1] = *(const bf16x8*)(base_ + n_*1024 + chS1);                 \
      }                                                                       \
    }
#define LDB2(buf)                                                             \
    {                                                                         \
      const __bf16* base_ = S + (buf)*24576 + 12288 + (wn*48 + 32 + l16) * 64;\
      bF[2][0] = *(const bf16x8*)(base_ + chS0);                              \
      bF[2][1] = *(const bf16x8*)(base_ + chS1);                              \
    }
#define MMA_N01(mh)                                                           \
    _Pragma("unroll") for (int m_ = 0; m_ < 3; ++m_)                          \
    _Pragma("unroll") for (int n_ = 0; n_ < 2; ++n_) {                        \
      acc[(mh)*3+m_][n_] = __builtin_amdgcn_mfma_f32_16x16x32_bf16(           \
          aF[m_][0], bF[n_][0], acc[(mh)*3+m_][n_], 0, 0, 0);                 \
      acc[(mh)*3+m_][n_] = __builtin_amdgcn_mfma_f32_16x16x32_bf16(           \
          aF[m_][1], bF[n_][1], acc[(mh)*3+m_][n_], 0, 0, 0);                 \
    }
#define MMA_N2(mh)                                                            \
    _Pragma("unroll") for (int m_ = 0; m_ < 3; ++m_) {                        \
      acc[(mh)*3+m_][2] = __builtin_amdgcn_mfma_f32_16x16x32_bf16(            \
          aF[m_][0], bF[2][0], acc[(mh)*3+m_][2], 0, 0, 0);                   \
      acc[(mh)*3+m_][2] = __builtin_amdgcn_mfma_f32_16x16x32_bf16(            \
          aF[m_][1], bF[2][1], acc[(mh)*3+m_][2], 0, 0, 0);                   \
    }
#define PHASE(MMA_STMT)                                                       \
    BAR(); __builtin_amdgcn_s_setprio(1); MMA_STMT;                           \
    __builtin_amdgcn_s_setprio(0); BAR();

    // ---- prologue: tile 0 fully (buf0) + tile 1's B0,B1,B2,A0 (buf1) ----
    stage_unit(A,  m0,      0, 0);
    stage_unit(A,  m0+64,   0, 512);
    stage_unit(A,  m0+128,  0, 1024);
    stage_unit(Bt, n0,      0, 1536);
    stage_unit(Bt, n0+64,   0, 2048);
    stage_unit(Bt, n0+128,  0, 2560);
    stage_unit(Bt, n0,     64, 3072+1536);
    stage_unit(Bt, n0+64,  64, 3072+2048);
    stage_unit(Bt, n0+128, 64, 3072+2560);
    stage_unit(A,  m0,     64, 3072);
    VMC(4);     // tile 0's 6 units done; tile 1's 4 stay in flight
    BAR();

    // ---- main loop: K-tiles 0..17 (9 iters x 2 tiles) ----
    for (int i = 0; i < 9; ++i) {
        const int ke = i * 128;        // k0 of even tile (buf0)
        const int ko = ke + 64;        // odd tile (buf1)
        const int kn = ke + 128;       // even-next (staged into buf0)
        const int km = ko + 128;       // odd-next  (staged into buf1)

        // P1
        LDA(0,0); LDB01(0);
        stage_unit(A, m0+64,  ko, 3072+512);    // A1(o)  [buf1.A dead since prev P7]
        stage_unit(A, m0+128, ko, 3072+1024);   // A2(o)
        PHASE(MMA_N01(0));
        // P2
        LDB2(0);
        PHASE(MMA_N2(0));
        // P3
        LDA(0,1);
        stage_unit(Bt, n0,    kn, 1536);        // B0(e+2) [buf0.B dead after P2]
        stage_unit(Bt, n0+64, kn, 2048);        // B1(e+2)
        PHASE(MMA_N01(1));
        // P4
        stage_unit(Bt, n0+128, kn, 2560);       // B2(e+2)
        stage_unit(A,  m0,     kn, 0);          // A0(e+2) [buf0.A dead after P3]
        VMC(4);                                 // tile o fully staged; B0/B1(e+2) in flight
        PHASE(MMA_N2(1));
        // P5
        LDA(1,0); LDB01(1);
        stage_unit(A, m0+64,  kn, 512);         // A1(e+2)
        stage_unit(A, m0+128, kn, 1024);        // A2(e+2)
        PHASE(MMA_N01(0));
        // P6
        LDB2(1);
        PHASE(MMA_N2(0));
        // P7
        LDA(1,1);
        stage_unit(Bt, n0,    km, 3072+1536);   // B0(o+2) [buf1.B dead after P6]
        stage_unit(Bt, n0+64, km, 3072+2048);   // B1(o+2)
        PHASE(MMA_N01(1));
        // P8
        stage_unit(Bt, n0+128, km, 3072+2560);  // B2(o+2)
        stage_unit(A,  m0,     km, 3072);       // A0(o+2) [buf1.A dead after P7]
        VMC(4);                                 // tile e+2 fully staged
        PHASE(MMA_N2(1));
    }

    // ---- epilogue: K-tiles 18 (buf0) and 19 (buf1), drain ----
    {
        // P1
        LDA(0,0); LDB01(0);
        stage_unit(A, m0+64,  1216, 3072+512);  // A1(19)
        stage_unit(A, m0+128, 1216, 3072+1024); // A2(19)
        PHASE(MMA_N01(0));
        // P2
        LDB2(0);
        PHASE(MMA_N2(0));
        // P3
        LDA(0,1);
        PHASE(MMA_N01(1));
        // P4
        VMC(0);                                 // tile 19 fully staged
        PHASE(MMA_N2(1));
        // P5
        LDA(1,0); LDB01(1);
        PHASE(MMA_N01(0));
        // P6
        LDB2(1);
        PHASE(MMA_N2(0));
        // P7
        LDA(1,1);
        PHASE(MMA_N01(1));
        // P8 (no trailing barrier needed; C-write reads registers only)
        __builtin_amdgcn_s_setprio(1);
        MMA_N2(1);
        __builtin_amdgcn_s_setprio(0);
    }

    // ---- C write: row = m0+wr*96+m*16+quad*4+r, col = n0+wn*48+n*16+l16 ----
#pragma unroll
    for (int n_ = 0; n_ < 3; ++n_) {
        const int col = n0 + wn * 48 + n_ * 16 + l16;
        const float bb = bias[col];
#pragma unroll
        for (int m_ = 0; m_ < 6; ++m_) {
            const int row = m0 + wr * 96 + m_ * 16 + quad * 4;
#pragma unroll
            for (int r = 0; r < 4; ++r)
                out[(size_t)(row + r) * QKV_N + col] = (__bf16)(acc[m_][n_][r] + bb);
        }
    }

#undef LDA
#undef LDB01
#undef LDB2
#undef MMA_N01
#undef MMA_N2
#undef PHASE
}

// ---------------------------------------------------------------------------
// Double-buffered m97-style GEMM (kept for the Wo projection):
// out[M,N] = A[M,1280] @ Bt[N,1280]^T + bias.
// ---------------------------------------------------------------------------
template<int BM, int BN, typename OutT>
__global__ __launch_bounds__(256) void gemm_bt_kernel(
    const __bf16* __restrict__ A,    // [M,1280]
    const __bf16* __restrict__ Bt,   // [N,1280]
    const float* __restrict__ bias,  // [N]
    OutT* __restrict__ out,          // [M,N]
    int N)
{
    constexpr int BK = 32;
    constexpr int WM = BM / 2, WN = BN / 2;
    constexpr int MT = WM / 16, NT = WN / 16;
    constexpr int KC = BK / 8;                       // 16B chunks per row (4)
    constexpr int ROUNDS = (BM + BN) * KC / 256;     // chunks per thread
    constexpr int ACH = BM * KC;                     // A chunks

    const int n0 = blockIdx.x * BN;
    const int m0 = blockIdx.y * BM;

    __shared__ __align__(16) __bf16 S[2][(BM + BN) * BK];

    const int tid  = threadIdx.x;
    const int wave = tid >> 6;
    const int lane = tid & 63;
    const int quad = lane >> 4;
    const int l16  = lane & 15;
    const int wm   = (wave >> 1) * WM;
    const int wn   = (wave & 1) * WN;

    f32x4 acc[MT][NT] = {};

    auto stage = [&](int k0, int p) {
#pragma unroll
        for (int r = 0; r < ROUNDS; ++r) {
            const int chunk = (r * 4 + wave) * 64 + lane;   // 16B chunk id
            const __bf16* g;
            if (chunk < ACH) {                 // wave-uniform (ACH % 256 == 0)
                g = A + (size_t)(m0 + chunk / KC) * 1280 + k0 + (chunk % KC) * 8;
            } else {
                const int c2 = chunk - ACH;
                g = Bt + (size_t)(n0 + c2 / KC) * 1280 + k0 + (c2 % KC) * 8;
            }
            async_copy16(g, &S[p][chunk * 8]);
        }
    };

    stage(0, 0);

    int p = 0;
    for (int k0 = 0; k0 < 1280; k0 += BK) {
        __syncthreads();
        if (k0 + BK < 1280) stage(k0 + BK, p ^ 1);

        const __bf16* As = S[p];
        const __bf16* Bs = S[p] + BM * BK;
        bf16x8 af[MT], bf[NT];
#pragma unroll
        for (int i = 0; i < MT; ++i)
            af[i] = *(const bf16x8*)(As + (wm + i * 16 + l16) * BK + quad * 8);
#pragma unroll
        for (int j = 0; j < NT; ++j)
            bf[j] = *(const bf16x8*)(Bs + (wn + j * 16 + l16) * BK + quad * 8);
#pragma unroll
        for (int mt = 0; mt < MT; ++mt)
#pragma unroll
            for (int nt = 0; nt < NT; ++nt)
                acc[mt][nt] = __builtin_amdgcn_mfma_f32_16x16x32_bf16(
                    af[mt], bf[nt], acc[mt][nt], 0, 0, 0);
        p ^= 1;
    }

#pragma unroll
    for (int nt = 0; nt < NT; ++nt) {
        const int col = n0 + wn + nt * 16 + l16;
        const float b = bias[col];
#pragma unroll
        for (int mt = 0; mt < MT; ++mt) {
#pragma unroll
            for (int r = 0; r < 4; ++r) {
                const int row = m0 + wm + mt * 16 + quad * 4 + r;
                out[(size_t)row * N + col] = (OutT)(acc[mt][nt][r] + b);
            }
        }
    }
}

// ---------------------------------------------------------------------------
// Fused rotary + windowed attention. One block per (window, head).
// ---------------------------------------------------------------------------
__global__ __launch_bounds__(256) void attn_win_kernel(
    const __bf16* __restrict__ qkv,   // [2304, 3840]
    const float* __restrict__ rope,   // [2304, 40]
    __bf16* __restrict__ attn_out)    // [2304, 1280]
{
    const int w = blockIdx.x;
    const int h = blockIdx.y;

    __shared__ __bf16 Qs[64 * 104];  // [t][d], d padded 80->96, stride 104
    __shared__ __bf16 Ks[64 * 104];
    __shared__ __bf16 Vt[80 * 72];   // [d][t], stride 72
    __shared__ __bf16 Ps[64 * 72];   // probs, stride 72

    const int tid = threadIdx.x;

    for (int u = tid; u < 320; u += 256) {
        const int t = u & 63;
        const int p = u >> 6;
        const int tg = w * 64 + t;
        const size_t base = (size_t)tg * QKV_N + h * HD;
        const int d0 = p * 8;

        bf16x8 qa = *(const bf16x8*)(qkv + base + d0);
        bf16x8 qb = *(const bf16x8*)(qkv + base + d0 + 40);
        bf16x8 ka = *(const bf16x8*)(qkv + base + HID + d0);
        bf16x8 kb = *(const bf16x8*)(qkv + base + HID + d0 + 40);
        bf16x8 va = *(const bf16x8*)(qkv + base + 2 * HID + d0);
        bf16x8 vb = *(const bf16x8*)(qkv + base + 2 * HID + d0 + 40);
        float4 r0 = *(const float4*)(rope + tg * 40 + d0);
        float4 r1 = *(const float4*)(rope + tg * 40 + d0 + 4);
        const float ang[8] = {r0.x, r0.y, r0.z, r0.w, r1.x, r1.y, r1.z, r1.w};

        bf16x8 qoa, qob, koa, kob;
#pragma unroll
        for (int j = 0; j < 8; ++j) {
            float sn, cs;
            __sincosf(ang[j], &sn, &cs);
            const float q0 = (float)qa[j], q1 = (float)qb[j];
            const float k0 = (float)ka[j], k1 = (float)kb[j];
            qoa[j] = (__bf16)(q0 * cs - q1 * sn);
            qob[j] = (__bf16)(q0 * sn + q1 * cs);
            koa[j] = (__bf16)(k0 * cs - k1 * sn);
            kob[j] = (__bf16)(k0 * sn + k1 * cs);
        }
        *(bf16x8*)(Qs + t * 104 + d0)      = qoa;
        *(bf16x8*)(Qs + t * 104 + d0 + 40) = qob;
        *(bf16x8*)(Ks + t * 104 + d0)      = koa;
        *(bf16x8*)(Ks + t * 104 + d0 + 40) = kob;
#pragma unroll
        for (int j = 0; j < 8; ++j) {
            Vt[(d0 + j) * 72 + t]      = va[j];
            Vt[(d0 + j + 40) * 72 + t] = vb[j];
        }
    }
    for (int idx = tid; idx < 64 * 16; idx += 256) {
        const int t = idx >> 4, d = 80 + (idx & 15);
        Qs[t * 104 + d] = (__bf16)0.f;
        Ks[t * 104 + d] = (__bf16)0.f;
    }
    __syncthreads();

    const int wave = tid >> 6, lane = tid & 63;
    const int quad = lane >> 4, l16 = lane & 15;

    // ---- S = Q K^T ----
    f32x4 sacc[4] = {};
#pragma unroll
    for (int k0 = 0; k0 < 96; k0 += 32) {
        bf16x8 af = *(const bf16x8*)(Qs + (wave * 16 + l16) * 104 + k0 + quad * 8);
#pragma unroll
        for (int ct = 0; ct < 4; ++ct) {
            bf16x8 bf = *(const bf16x8*)(Ks + (ct * 16 + l16) * 104 + k0 + quad * 8);
            sacc[ct] = __builtin_amdgcn_mfma_f32_16x16x32_bf16(af, bf, sacc[ct], 0, 0, 0);
        }
    }

    // ---- in-register softmax over the 16-lane row group ----
    const float scale = 0.11180339887498948f;  // 1/sqrt(80)
#pragma unroll
    for (int r = 0; r < 4; ++r) {
        float m = -1e30f;
#pragma unroll
        for (int ct = 0; ct < 4; ++ct) {
            sacc[ct][r] *= scale;
            m = fmaxf(m, sacc[ct][r]);
        }
        m = fmaxf(m, __shfl_xor(m, 1));
        m = fmaxf(m, __shfl_xor(m, 2));
        m = fmaxf(m, __shfl_xor(m, 4));
        m = fmaxf(m, __shfl_xor(m, 8));
        float e[4], s = 0.f;
#pragma unroll
        for (int ct = 0; ct < 4; ++ct) {
            e[ct] = __expf(sacc[ct][r] - m);
            s += e[ct];
        }
        s += __shfl_xor(s, 1);
        s += __shfl_xor(s, 2);
        s += __shfl_xor(s, 4);
        s += __shfl_xor(s, 8);
        const float inv = 1.0f / s;
        const int row = wave * 16 + quad * 4 + r;
#pragma unroll
        for (int ct = 0; ct < 4; ++ct)
            Ps[row * 72 + ct * 16 + l16] = (__bf16)(e[ct] * inv);
    }
    __syncthreads();

    // ---- O = P V ----
    f32x4 oacc[5] = {};
#pragma unroll
    for (int k0 = 0; k0 < 64; k0 += 32) {
        bf16x8 af = *(const bf16x8*)(Ps + (wave * 16 + l16) * 72 + k0 + quad * 8);
#pragma unroll
        for (int nt = 0; nt < 5; ++nt) {
            bf16x8 bf = *(const bf16x8*)(Vt + (nt * 16 + l16) * 72 + k0 + quad * 8);
            oacc[nt] = __builtin_amdgcn_mfma_f32_16x16x32_bf16(af, bf, oacc[nt], 0, 0, 0);
        }
    }
#pragma unroll
    for (int nt = 0; nt < 5; ++nt) {
        const int d = nt * 16 + l16;
#pragma unroll
        for (int r = 0; r < 4; ++r) {
            const int t = w * 64 + wave * 16 + quad * 4 + r;
            attn_out[(size_t)t * HID + h * HD + d] = (__bf16)oacc[nt][r];
        }
    }
}

// ---------------------------------------------------------------------------
extern "C" void kernel_launch(void* const* d_in, const int* in_sizes, int n_in,
                              void* d_out, int out_size, void* d_ws, size_t ws_size,
                              hipStream_t stream) {
    const float* x    = (const float*)d_in[0];
    const float* rope = (const float*)d_in[1];
    // d_in[2] = cu_window_seqlens (statically: 36 full 64-token windows)
    const float* Wqkv = (const float*)d_in[3];
    const float* bqkv = (const float*)d_in[4];
    const float* Wo   = (const float*)d_in[5];
    const float* bo   = (const float*)d_in[6];
    float* out = (float*)d_out;

    char* ws = (char*)d_ws;
    const size_t szXb = (size_t)T_TOK * HID * 2;
    const size_t szWq = (size_t)QKV_N * HID * 2;
    const size_t szWo = (size_t)HID * HID * 2;
    __bf16* Xb      = (__bf16*)ws;
    __bf16* Wqkv_t  = (__bf16*)(ws + szXb);
    __bf16* Wo_t    = (__bf16*)(ws + szXb + szWq);
    __bf16* qkv_bf  = (__bf16*)(ws + szXb + szWq + szWo);
    __bf16* attn_bf = (__bf16*)ws;   // aliases Xb (dead after gemm_qkv)

    prep_kernel<<<NB_CONV + NB_WQKV + NB_WO, 256, 0, stream>>>(
        x, Xb, Wqkv, Wqkv_t, Wo, Wo_t);

    // 192x192x64 8-phase counted-vmcnt pipeline: 240 blocks
    gemm192_kernel<<<dim3(QKV_N / 192, T_TOK / 192), 512, 0, stream>>>(
        Xb, Wqkv_t, bqkv, qkv_bf);

    attn_win_kernel<<<dim3(NWIN, NH), 256, 0, stream>>>(qkv_bf, rope, attn_bf);

    // 128x128x32 dbuf: 180 blocks
    gemm_bt_kernel<128, 128, float><<<dim3(HID / 128, T_TOK / 128), 256, 0, stream>>>(
        attn_bf, Wo_t, bo, out, HID);
}

// Round 2
// 151.939 us; speedup vs baseline: 1.0604x; 1.0202x over previous
//
#include <hip/hip_runtime.h>
#include <hip/hip_bf16.h>

typedef __bf16 bf16x8 __attribute__((ext_vector_type(8)));
typedef __bf16 bf16x4v __attribute__((ext_vector_type(4)));
typedef float  f32x4  __attribute__((ext_vector_type(4)));

#define T_TOK   2304
#define HID     1280
#define QKV_N   3840
#define NH      16
#define HD      80
#define NWIN    36

// ---------------------------------------------------------------------------
// async global->LDS 16B copy (wave-uniform LDS base + lane*16 semantics)
// ---------------------------------------------------------------------------
__device__ inline void async_copy16(const __bf16* g, __bf16* l) {
    __builtin_amdgcn_global_load_lds(
        (const __attribute__((address_space(1))) unsigned int*)g,
        (__attribute__((address_space(3))) unsigned int*)l, 16, 0, 0);
}

// ---------------------------------------------------------------------------
// prep: range0 converts x fp32->bf16; range1/2 transpose-convert Wqkv / Wo
// to B^T bf16 layout. Single launch, 3-range 1D grid.
// ---------------------------------------------------------------------------
#define NB_CONV 1440   // 2304*1280 / (256*8)
#define NB_WQKV 1200   // (1280/64) * (3840/64)
#define NB_WO    400   // (1280/64) * (1280/64)

__global__ __launch_bounds__(256) void prep_kernel(
    const float* __restrict__ x,    __bf16* __restrict__ Xb,
    const float* __restrict__ Wqkv, __bf16* __restrict__ Wqkv_t,
    const float* __restrict__ Wo,   __bf16* __restrict__ Wo_t)
{
    __shared__ float t[64][65];
    int b = blockIdx.x;
    const int tid = threadIdx.x;

    if (b < NB_CONV) {
        const int i = (b * 256 + tid) * 8;
        const float4* p = (const float4*)(x + i);
        float4 a0 = p[0], a1 = p[1];
        bf16x8 o;
        o[0] = (__bf16)a0.x; o[1] = (__bf16)a0.y; o[2] = (__bf16)a0.z; o[3] = (__bf16)a0.w;
        o[4] = (__bf16)a1.x; o[5] = (__bf16)a1.y; o[6] = (__bf16)a1.z; o[7] = (__bf16)a1.w;
        *(bf16x8*)(Xb + i) = o;
        return;
    }

    const float* in; __bf16* out; int C, c0, r0;
    const int R = 1280;
    if (b < NB_CONV + NB_WQKV) {
        b -= NB_CONV;
        in = Wqkv; out = Wqkv_t; C = QKV_N;
        c0 = (b % 60) * 64; r0 = (b / 60) * 64;
    } else {
        b -= NB_CONV + NB_WQKV;
        in = Wo; out = Wo_t; C = HID;
        c0 = (b % 20) * 64; r0 = (b / 20) * 64;
    }

    const int lr = tid >> 4;
    const int lc = (tid & 15) * 4;
#pragma unroll
    for (int i = 0; i < 4; ++i) {
        float4 v = *(const float4*)(in + (size_t)(r0 + lr + i * 16) * C + c0 + lc);
        float* d = &t[lr + i * 16][lc];
        d[0] = v.x; d[1] = v.y; d[2] = v.z; d[3] = v.w;
    }
    __syncthreads();
    const int oc  = tid >> 4;
    const int orr = (tid & 15) * 4;
#pragma unroll
    for (int i = 0; i < 4; ++i) {
        const int c = oc + i * 16;
        bf16x4v o;
        o[0] = (__bf16)t[orr + 0][c];
        o[1] = (__bf16)t[orr + 1][c];
        o[2] = (__bf16)t[orr + 2][c];
        o[3] = (__bf16)t[orr + 3][c];
        *(bf16x4v*)(out + (size_t)(c0 + c) * R + r0 + orr) = o;
    }
}

// ---------------------------------------------------------------------------
// Overlapped deep-pipelined GEMM for QKV: out[2304,3840] = A[2304,1280] @
// Bt[3840,1280]^T + bias.  BM=BN=192, BK=64, 8 waves (2M x 4N, per-wave
// 96x48), grid 20x12 = 240 blocks.
//
// Per K-tile t (buf p = t&1), fragment-double-buffered schedule:
//   A: issue ds_read aHi(t)                 [6 b128, in flight under MFMA]
//   C: MFMA mh0 (aLo x bF[p])               [18 MFMA; compiler waits only
//                                            on aLo/bF, aHi stays in flight]
//   D: lgkmcnt(0) + sched_barrier           [all my reads of buf p done]
//   E: s_barrier                            [everyone done reading buf p]
//   F: stage tile t+2 -> buf p              [6 global_load_lds units]
//   G: vmcnt(6) + sched_barrier             [tile t+1's 6 units landed;
//                                            t+2's 6 stay in flight - never 0]
//   H: s_barrier                            [t+1 visible to all]
//   I: issue ds_read aLo/bF[p^1] (tile t+1) [12 b128]
//   J: MFMA mh1 (aHi x bF[p])               [18 MFMA, overlaps I's reads]
// 2 barriers per K-tile (40 total). MFMA clusters are register-only and may
// float into the wait windows - harmless and helpful. bF is parity-indexed
// (static) so tile t+1's B loads never clobber tile t's live set.
// LDS XOR swizzle: read chunk = quad ^ (row&7); inverse applied to the
// global source k-offset (global_load_lds dest stays linear).
// ---------------------------------------------------------------------------
#define SB0()   __builtin_amdgcn_sched_barrier(0)
#define BARR()  __builtin_amdgcn_s_barrier()
#define LGKM0() asm volatile("s_waitcnt lgkmcnt(0)" ::: "memory")
#define VMC(n)  asm volatile("s_waitcnt vmcnt(" #n ")" ::: "memory")

__global__ __launch_bounds__(512, 2) void gemm192_kernel(
    const __bf16* __restrict__ A,    // [2304,1280]
    const __bf16* __restrict__ Bt,   // [3840,1280]
    const float* __restrict__ bias,  // [3840]
    __bf16* __restrict__ out)        // [2304,3840]
{
    // 2 bufs x (A 192x64 + B 192x64) bf16 = 96 KiB
    __shared__ __align__(16) __bf16 S[49152];

    const int tid  = threadIdx.x;
    const int wave = tid >> 6, lane = tid & 63;
    const int quad = lane >> 4, l16 = lane & 15;
    const int wr = wave >> 2, wn = wave & 3;
    const int m0 = blockIdx.y * 192;
    const int n0 = blockIdx.x * 192;

    // staging: row-in-unit = tid>>3; dest col chunk = tid&7;
    // source k-chunk = (tid&7) ^ (row&7)  (inverse swizzle on global addr)
    const int rloc = tid >> 3;
    const int kcol = ((tid & 7) ^ (rloc & 7)) * 8;

    auto stage_unit = [&](const __bf16* g, int grow, int k0, int chunk0) {
        async_copy16(g + (size_t)(grow + rloc) * 1280 + (k0 + kcol),
                     S + (chunk0 + tid) * 8);
    };

    // ds-read swizzled chunk offsets (elements) for ksub 0 / 1
    const int chS0 = ((quad) ^ (l16 & 7)) * 8;
    const int chS1 = ((4 + quad) ^ (l16 & 7)) * 8;

    bf16x8 aLo[3][2], aHi[3][2], bFb[2][3][2];
    f32x4 acc[6][3] = {};

#define LDAf(buf, mh, dst)                                                    \
    {                                                                         \
      const __bf16* baseA_ = S + (buf)*24576 + (wr*96 + (mh)*48 + l16) * 64;  \
      _Pragma("unroll") for (int m_ = 0; m_ < 3; ++m_) {                      \
        dst[m_][0] = *(const bf16x8*)(baseA_ + m_*1024 + chS0);               \
        dst[m_][1] = *(const bf16x8*)(baseA_ + m_*1024 + chS1);               \
      }                                                                       \
    }
#define LDBf(buf, dst)                                                        \
    {                                                                         \
      const __bf16* baseB_ = S + (buf)*24576 + 12288 + (wn*48 + l16) * 64;    \
      _Pragma("unroll") for (int n_ = 0; n_ < 3; ++n_) {                      \
        dst[n_][0] = *(const bf16x8*)(baseB_ + n_*1024 + chS0);               \
        dst[n_][1] = *(const bf16x8*)(baseB_ + n_*1024 + chS1);               \
      }                                                                       \
    }
#define MMAC(mh, aA, bA)                                                      \
    _Pragma("unroll") for (int m_ = 0; m_ < 3; ++m_)                          \
    _Pragma("unroll") for (int n_ = 0; n_ < 3; ++n_) {                        \
      acc[(mh)*3+m_][n_] = __builtin_amdgcn_mfma_f32_16x16x32_bf16(           \
          aA[m_][0], bA[n_][0], acc[(mh)*3+m_][n_], 0, 0, 0);                 \
      acc[(mh)*3+m_][n_] = __builtin_amdgcn_mfma_f32_16x16x32_bf16(           \
          aA[m_][1], bA[n_][1], acc[(mh)*3+m_][n_], 0, 0, 0);                 \
    }
#define STAGE6(buf, k0)                                                       \
    stage_unit(A,  m0,      (k0), (buf)*3072 + 0);                            \
    stage_unit(A,  m0+64,   (k0), (buf)*3072 + 512);                          \
    stage_unit(A,  m0+128,  (k0), (buf)*3072 + 1024);                         \
    stage_unit(Bt, n0,      (k0), (buf)*3072 + 1536);                         \
    stage_unit(Bt, n0+64,   (k0), (buf)*3072 + 2048);                         \
    stage_unit(Bt, n0+128,  (k0), (buf)*3072 + 2560);

#define TILE(p, kt2)                                                          \
    LDAf(p, 1, aHi);                                                          \
    __builtin_amdgcn_s_setprio(1); MMAC(0, aLo, bFb[p]);                      \
    __builtin_amdgcn_s_setprio(0);                                            \
    LGKM0(); SB0();                                                           \
    BARR();                                                                   \
    STAGE6(p, kt2);                                                           \
    VMC(6); SB0();                                                            \
    BARR();                                                                   \
    LDAf(p^1, 0, aLo); LDBf(p^1, bFb[p^1]);                                   \
    __builtin_amdgcn_s_setprio(1); MMAC(1, aHi, bFb[p]);                      \
    __builtin_amdgcn_s_setprio(0);

    // ---- prologue: stage tiles 0,1; load tile 0's set0 fragments ----
    STAGE6(0, 0);
    STAGE6(1, 64);
    VMC(6); SB0();     // tile 0's 6 units done; tile 1's stay in flight
    BARR();
    LDAf(0, 0, aLo); LDBf(0, bFb[0]);

    // ---- main loop: K-tiles 0..17 (9 iters x 2 tiles), staging 2..19 ----
    for (int i = 0; i < 9; ++i) {
        const int kt2 = i * 128 + 128;   // k0 of tile 2i+2
        TILE(0, kt2)
        TILE(1, kt2 + 64)
    }

    // ---- epilogue: tiles 18 (buf0) and 19 (buf1), no staging ----
    LDAf(0, 1, aHi);
    __builtin_amdgcn_s_setprio(1); MMAC(0, aLo, bFb[0]);
    __builtin_amdgcn_s_setprio(0);
    LGKM0(); SB0();
    VMC(0); SB0();                     // tile 19's units (issued i=8) done
    BARR();
    LDAf(1, 0, aLo); LDBf(1, bFb[1]);
    __builtin_amdgcn_s_setprio(1); MMAC(1, aHi, bFb[0]);
    __builtin_amdgcn_s_setprio(0);
    // tile 19
    LDAf(1, 1, aHi);
    __builtin_amdgcn_s_setprio(1); MMAC(0, aLo, bFb[1]);
    __builtin_amdgcn_s_setprio(0);
    __builtin_amdgcn_s_setprio(1); MMAC(1, aHi, bFb[1]);
    __builtin_amdgcn_s_setprio(0);

    // ---- C write: row = m0+wr*96+m*16+quad*4+r, col = n0+wn*48+n*16+l16 ----
#pragma unroll
    for (int n_ = 0; n_ < 3; ++n_) {
        const int col = n0 + wn * 48 + n_ * 16 + l16;
        const float bb = bias[col];
#pragma unroll
        for (int m_ = 0; m_ < 6; ++m_) {
            const int row = m0 + wr * 96 + m_ * 16 + quad * 4;
#pragma unroll
            for (int r = 0; r < 4; ++r)
                out[(size_t)(row + r) * QKV_N + col] = (__bf16)(acc[m_][n_][r] + bb);
        }
    }

#undef LDAf
#undef LDBf
#undef MMAC
#undef STAGE6
#undef TILE
}

// ---------------------------------------------------------------------------
// Double-buffered m97-style GEMM (kept for the Wo projection):
// out[M,N] = A[M,1280] @ Bt[N,1280]^T + bias.
// ---------------------------------------------------------------------------
template<int BM, int BN, typename OutT>
__global__ __launch_bounds__(256) void gemm_bt_kernel(
    const __bf16* __restrict__ A,    // [M,1280]
    const __bf16* __restrict__ Bt,   // [N,1280]
    const float* __restrict__ bias,  // [N]
    OutT* __restrict__ out,          // [M,N]
    int N)
{
    constexpr int BK = 32;
    constexpr int WM = BM / 2, WN = BN / 2;
    constexpr int MT = WM / 16, NT = WN / 16;
    constexpr int KC = BK / 8;                       // 16B chunks per row (4)
    constexpr int ROUNDS = (BM + BN) * KC / 256;     // chunks per thread
    constexpr int ACH = BM * KC;                     // A chunks

    const int n0 = blockIdx.x * BN;
    const int m0 = blockIdx.y * BM;

    __shared__ __align__(16) __bf16 S[2][(BM + BN) * BK];

    const int tid  = threadIdx.x;
    const int wave = tid >> 6;
    const int lane = tid & 63;
    const int quad = lane >> 4;
    const int l16  = lane & 15;
    const int wm   = (wave >> 1) * WM;
    const int wn   = (wave & 1) * WN;

    f32x4 acc[MT][NT] = {};

    auto stage = [&](int k0, int p) {
#pragma unroll
        for (int r = 0; r < ROUNDS; ++r) {
            const int chunk = (r * 4 + wave) * 64 + lane;   // 16B chunk id
            const __bf16* g;
            if (chunk < ACH) {                 // wave-uniform (ACH % 256 == 0)
                g = A + (size_t)(m0 + chunk / KC) * 1280 + k0 + (chunk % KC) * 8;
            } else {
                const int c2 = chunk - ACH;
                g = Bt + (size_t)(n0 + c2 / KC) * 1280 + k0 + (c2 % KC) * 8;
            }
            async_copy16(g, &S[p][chunk * 8]);
        }
    };

    stage(0, 0);

    int p = 0;
    for (int k0 = 0; k0 < 1280; k0 += BK) {
        __syncthreads();
        if (k0 + BK < 1280) stage(k0 + BK, p ^ 1);

        const __bf16* As = S[p];
        const __bf16* Bs = S[p] + BM * BK;
        bf16x8 af[MT], bf[NT];
#pragma unroll
        for (int i = 0; i < MT; ++i)
            af[i] = *(const bf16x8*)(As + (wm + i * 16 + l16) * BK + quad * 8);
#pragma unroll
        for (int j = 0; j < NT; ++j)
            bf[j] = *(const bf16x8*)(Bs + (wn + j * 16 + l16) * BK + quad * 8);
#pragma unroll
        for (int mt = 0; mt < MT; ++mt)
#pragma unroll
            for (int nt = 0; nt < NT; ++nt)
                acc[mt][nt] = __builtin_amdgcn_mfma_f32_16x16x32_bf16(
                    af[mt], bf[nt], acc[mt][nt], 0, 0, 0);
        p ^= 1;
    }

#pragma unroll
    for (int nt = 0; nt < NT; ++nt) {
        const int col = n0 + wn + nt * 16 + l16;
        const float b = bias[col];
#pragma unroll
        for (int mt = 0; mt < MT; ++mt) {
#pragma unroll
            for (int r = 0; r < 4; ++r) {
                const int row = m0 + wm + mt * 16 + quad * 4 + r;
                out[(size_t)row * N + col] = (OutT)(acc[mt][nt][r] + b);
            }
        }
    }
}

// ---------------------------------------------------------------------------
// Fused rotary + windowed attention. One block per (window, head).
// ---------------------------------------------------------------------------
__global__ __launch_bounds__(256) void attn_win_kernel(
    const __bf16* __restrict__ qkv,   // [2304, 3840]
    const float* __restrict__ rope,   // [2304, 40]
    __bf16* __restrict__ attn_out)    // [2304, 1280]
{
    const int w = blockIdx.x;
    const int h = blockIdx.y;

    __shared__ __bf16 Qs[64 * 104];  // [t][d], d padded 80->96, stride 104
    __shared__ __bf16 Ks[64 * 104];
    __shared__ __bf16 Vt[80 * 72];   // [d][t], stride 72
    __shared__ __bf16 Ps[64 * 72];   // probs, stride 72

    const int tid = threadIdx.x;

    for (int u = tid; u < 320; u += 256) {
        const int t = u & 63;
        const int p = u >> 6;
        const int tg = w * 64 + t;
        const size_t base = (size_t)tg * QKV_N + h * HD;
        const int d0 = p * 8;

        bf16x8 qa = *(const bf16x8*)(qkv + base + d0);
        bf16x8 qb = *(const bf16x8*)(qkv + base + d0 + 40);
        bf16x8 ka = *(const bf16x8*)(qkv + base + HID + d0);
        bf16x8 kb = *(const bf16x8*)(qkv + base + HID + d0 + 40);
        bf16x8 va = *(const bf16x8*)(qkv + base + 2 * HID + d0);
        bf16x8 vb = *(const bf16x8*)(qkv + base + 2 * HID + d0 + 40);
        float4 r0 = *(const float4*)(rope + tg * 40 + d0);
        float4 r1 = *(const float4*)(rope + tg * 40 + d0 + 4);
        const float ang[8] = {r0.x, r0.y, r0.z, r0.w, r1.x, r1.y, r1.z, r1.w};

        bf16x8 qoa, qob, koa, kob;
#pragma unroll
        for (int j = 0; j < 8; ++j) {
            float sn, cs;
            __sincosf(ang[j], &sn, &cs);
            const float q0 = (float)qa[j], q1 = (float)qb[j];
            const float k0 = (float)ka[j], k1 = (float)kb[j];
            qoa[j] = (__bf16)(q0 * cs - q1 * sn);
            qob[j] = (__bf16)(q0 * sn + q1 * cs);
            koa[j] = (__bf16)(k0 * cs - k1 * sn);
            kob[j] = (__bf16)(k0 * sn + k1 * cs);
        }
        *(bf16x8*)(Qs + t * 104 + d0)      = qoa;
        *(bf16x8*)(Qs + t * 104 + d0 + 40) = qob;
        *(bf16x8*)(Ks + t * 104 + d0)      = koa;
        *(bf16x8*)(Ks + t * 104 + d0 + 40) = kob;
#pragma unroll
        for (int j = 0; j < 8; ++j) {
            Vt[(d0 + j) * 72 + t]      = va[j];
            Vt[(d0 + j + 40) * 72 + t] = vb[j];
        }
    }
    for (int idx = tid; idx < 64 * 16; idx += 256) {
        const int t = idx >> 4, d = 80 + (idx & 15);
        Qs[t * 104 + d] = (__bf16)0.f;
        Ks[t * 104 + d] = (__bf16)0.f;
    }
    __syncthreads();

    const int wave = tid >> 6, lane = tid & 63;
    const int quad = lane >> 4, l16 = lane & 15;

    // ---- S = Q K^T ----
    f32x4 sacc[4] = {};
#pragma unroll
    for (int k0 = 0; k0 < 96; k0 += 32) {
        bf16x8 af = *(const bf16x8*)(Qs + (wave * 16 + l16) * 104 + k0 + quad * 8);
#pragma unroll
        for (int ct = 0; ct < 4; ++ct) {
            bf16x8 bf = *(const bf16x8*)(Ks + (ct * 16 + l16) * 104 + k0 + quad * 8);
            sacc[ct] = __builtin_amdgcn_mfma_f32_16x16x32_bf16(af, bf, sacc[ct], 0, 0, 0);
        }
    }

    // ---- in-register softmax over the 16-lane row group ----
    const float scale = 0.11180339887498948f;  // 1/sqrt(80)
#pragma unroll
    for (int r = 0; r < 4; ++r) {
        float m = -1e30f;
#pragma unroll
        for (int ct = 0; ct < 4; ++ct) {
            sacc[ct][r] *= scale;
            m = fmaxf(m, sacc[ct][r]);
        }
        m = fmaxf(m, __shfl_xor(m, 1));
        m = fmaxf(m, __shfl_xor(m, 2));
        m = fmaxf(m, __shfl_xor(m, 4));
        m = fmaxf(m, __shfl_xor(m, 8));
        float e[4], s = 0.f;
#pragma unroll
        for (int ct = 0; ct < 4; ++ct) {
            e[ct] = __expf(sacc[ct][r] - m);
            s += e[ct];
        }
        s += __shfl_xor(s, 1);
        s += __shfl_xor(s, 2);
        s += __shfl_xor(s, 4);
        s += __shfl_xor(s, 8);
        const float inv = 1.0f / s;
        const int row = wave * 16 + quad * 4 + r;
#pragma unroll
        for (int ct = 0; ct < 4; ++ct)
            Ps[row * 72 + ct * 16 + l16] = (__bf16)(e[ct] * inv);
    }
    __syncthreads();

    // ---- O = P V ----
    f32x4 oacc[5] = {};
#pragma unroll
    for (int k0 = 0; k0 < 64; k0 += 32) {
        bf16x8 af = *(const bf16x8*)(Ps + (wave * 16 + l16) * 72 + k0 + quad * 8);
#pragma unroll
        for (int nt = 0; nt < 5; ++nt) {
            bf16x8 bf = *(const bf16x8*)(Vt + (nt * 16 + l16) * 72 + k0 + quad * 8);
            oacc[nt] = __builtin_amdgcn_mfma_f32_16x16x32_bf16(af, bf, oacc[nt], 0, 0, 0);
        }
    }
#pragma unroll
    for (int nt = 0; nt < 5; ++nt) {
        const int d = nt * 16 + l16;
#pragma unroll
        for (int r = 0; r < 4; ++r) {
            const int t = w * 64 + wave * 16 + quad * 4 + r;
            attn_out[(size_t)t * HID + h * HD + d] = (__bf16)oacc[nt][r];
        }
    }
}

// ---------------------------------------------------------------------------
extern "C" void kernel_launch(void* const* d_in, const int* in_sizes, int n_in,
                              void* d_out, int out_size, void* d_ws, size_t ws_size,
                              hipStream_t stream) {
    const float* x    = (const float*)d_in[0];
    const float* rope = (const float*)d_in[1];
    // d_in[2] = cu_window_seqlens (statically: 36 full 64-token windows)
    const float* Wqkv = (const float*)d_in[3];
    const float* bqkv = (const float*)d_in[4];
    const float* Wo   = (const float*)d_in[5];
    const float* bo   = (const float*)d_in[6];
    float* out = (float*)d_out;

    char* ws = (char*)d_ws;
    const size_t szXb = (size_t)T_TOK * HID * 2;
    const size_t szWq = (size_t)QKV_N * HID * 2;
    const size_t szWo = (size_t)HID * HID * 2;
    __bf16* Xb      = (__bf16*)ws;
    __bf16* Wqkv_t  = (__bf16*)(ws + szXb);
    __bf16* Wo_t    = (__bf16*)(ws + szXb + szWq);
    __bf16* qkv_bf  = (__bf16*)(ws + szXb + szWq + szWo);
    __bf16* attn_bf = (__bf16*)ws;   // aliases Xb (dead after gemm_qkv)

    prep_kernel<<<NB_CONV + NB_WQKV + NB_WO, 256, 0, stream>>>(
        x, Xb, Wqkv, Wqkv_t, Wo, Wo_t);

    // 192x192x64 fragment-double-buffered pipeline: 240 blocks
    gemm192_kernel<<<dim3(QKV_N / 192, T_TOK / 192), 512, 0, stream>>>(
        Xb, Wqkv_t, bqkv, qkv_bf);

    attn_win_kernel<<<dim3(NWIN, NH), 256, 0, stream>>>(qkv_bf, rope, attn_bf);

    // 64x128x32 dbuf: 360 blocks (known-good from the 161us baseline)
    gemm_bt_kernel<64, 128, float><<<dim3(HID / 128, T_TOK / 64), 256, 0, stream>>>(
        attn_bf, Wo_t, bo, out, HID);
}

// Round 3
// 144.576 us; speedup vs baseline: 1.1144x; 1.0509x over previous
//
#include <hip/hip_runtime.h>
#include <hip/hip_bf16.h>

typedef __bf16 bf16x8 __attribute__((ext_vector_type(8)));
typedef __bf16 bf16x4v __attribute__((ext_vector_type(4)));
typedef float  f32x4  __attribute__((ext_vector_type(4)));

#define T_TOK   2304
#define HID     1280
#define QKV_N   3840
#define NH      16
#define HD      80
#define NWIN    36

// ---------------------------------------------------------------------------
// async global->LDS 16B copy (wave-uniform LDS base + lane*16 semantics)
// ---------------------------------------------------------------------------
__device__ inline void async_copy16(const __bf16* g, __bf16* l) {
    __builtin_amdgcn_global_load_lds(
        (const __attribute__((address_space(1))) unsigned int*)g,
        (__attribute__((address_space(3))) unsigned int*)l, 16, 0, 0);
}

// ---------------------------------------------------------------------------
// prep: range0 converts x fp32->bf16; range1/2 transpose-convert Wqkv / Wo
// to B^T bf16 layout. Single launch, 3-range 1D grid.
// ---------------------------------------------------------------------------
#define NB_CONV 1440   // 2304*1280 / (256*8)
#define NB_WQKV 1200   // (1280/64) * (3840/64)
#define NB_WO    400   // (1280/64) * (1280/64)

__global__ __launch_bounds__(256) void prep_kernel(
    const float* __restrict__ x,    __bf16* __restrict__ Xb,
    const float* __restrict__ Wqkv, __bf16* __restrict__ Wqkv_t,
    const float* __restrict__ Wo,   __bf16* __restrict__ Wo_t)
{
    __shared__ float t[64][65];
    int b = blockIdx.x;
    const int tid = threadIdx.x;

    if (b < NB_CONV) {
        const int i = (b * 256 + tid) * 8;
        const float4* p = (const float4*)(x + i);
        float4 a0 = p[0], a1 = p[1];
        bf16x8 o;
        o[0] = (__bf16)a0.x; o[1] = (__bf16)a0.y; o[2] = (__bf16)a0.z; o[3] = (__bf16)a0.w;
        o[4] = (__bf16)a1.x; o[5] = (__bf16)a1.y; o[6] = (__bf16)a1.z; o[7] = (__bf16)a1.w;
        *(bf16x8*)(Xb + i) = o;
        return;
    }

    const float* in; __bf16* out; int C, c0, r0;
    const int R = 1280;
    if (b < NB_CONV + NB_WQKV) {
        b -= NB_CONV;
        in = Wqkv; out = Wqkv_t; C = QKV_N;
        c0 = (b % 60) * 64; r0 = (b / 60) * 64;
    } else {
        b -= NB_CONV + NB_WQKV;
        in = Wo; out = Wo_t; C = HID;
        c0 = (b % 20) * 64; r0 = (b / 20) * 64;
    }

    const int lr = tid >> 4;
    const int lc = (tid & 15) * 4;
#pragma unroll
    for (int i = 0; i < 4; ++i) {
        float4 v = *(const float4*)(in + (size_t)(r0 + lr + i * 16) * C + c0 + lc);
        float* d = &t[lr + i * 16][lc];
        d[0] = v.x; d[1] = v.y; d[2] = v.z; d[3] = v.w;
    }
    __syncthreads();
    const int oc  = tid >> 4;
    const int orr = (tid & 15) * 4;
#pragma unroll
    for (int i = 0; i < 4; ++i) {
        const int c = oc + i * 16;
        bf16x4v o;
        o[0] = (__bf16)t[orr + 0][c];
        o[1] = (__bf16)t[orr + 1][c];
        o[2] = (__bf16)t[orr + 2][c];
        o[3] = (__bf16)t[orr + 3][c];
        *(bf16x4v*)(out + (size_t)(c0 + c) * R + r0 + orr) = o;
    }
}

// ---------------------------------------------------------------------------
// Overlapped deep-pipelined GEMM for QKV: out[2304,3840] = A[2304,1280] @
// Bt[3840,1280]^T + bias.  BM=BN=192, BK=64, 8 waves (2M x 4N, per-wave
// 96x48), grid 20x12 = 240 blocks, XCD-swizzled.
//
// Per K-tile t (buf p = t&1), fragment-double-buffered schedule:
//   issue ds_read aHi(t) -> MFMA mh0 (reads in flight under it) ->
//   lgkmcnt(0) -> barrier -> stage tile t+2 -> vmcnt(6) (counted; t+1 landed,
//   t+2 in flight) -> barrier -> issue ds_read aLo/bF(t+1) -> MFMA mh1.
// 2 barriers per K-tile. bF parity-indexed (static) so t+1's B loads never
// clobber tile t's live set. LDS XOR swizzle on reads; inverse applied to
// the global source k-offset (global_load_lds dest stays linear).
// ---------------------------------------------------------------------------
#define SB0()   __builtin_amdgcn_sched_barrier(0)
#define BARR()  __builtin_amdgcn_s_barrier()
#define LGKM0() asm volatile("s_waitcnt lgkmcnt(0)" ::: "memory")
#define VMC(n)  asm volatile("s_waitcnt vmcnt(" #n ")" ::: "memory")

__global__ __launch_bounds__(512, 2) void gemm192_kernel(
    const __bf16* __restrict__ A,    // [2304,1280]
    const __bf16* __restrict__ Bt,   // [3840,1280]
    const float* __restrict__ bias,  // [3840]
    __bf16* __restrict__ out)        // [2304,3840]
{
    // 2 bufs x (A 192x64 + B 192x64) bf16 = 96 KiB
    __shared__ __align__(16) __bf16 S[49152];

    const int tid  = threadIdx.x;
    const int wave = tid >> 6, lane = tid & 63;
    const int quad = lane >> 4, l16 = lane & 15;
    const int wr = wave >> 2, wn = wave & 3;

    // XCD-aware bijective swizzle: 240 = 8 XCDs x 30; column-major decompose
    // so each XCD's 30 blocks reuse ~2.5 B-panels 12x in its private L2.
    const int lin = blockIdx.y * 20 + blockIdx.x;
    const int swz = (lin & 7) * 30 + (lin >> 3);
    const int m0 = (swz % 12) * 192;
    const int n0 = (swz / 12) * 192;

    // staging: row-in-unit = tid>>3; dest col chunk = tid&7;
    // source k-chunk = (tid&7) ^ (row&7)  (inverse swizzle on global addr)
    const int rloc = tid >> 3;
    const int kcol = ((tid & 7) ^ (rloc & 7)) * 8;

    auto stage_unit = [&](const __bf16* g, int grow, int k0, int chunk0) {
        async_copy16(g + (size_t)(grow + rloc) * 1280 + (k0 + kcol),
                     S + (chunk0 + tid) * 8);
    };

    // ds-read swizzled chunk offsets (elements) for ksub 0 / 1
    const int chS0 = ((quad) ^ (l16 & 7)) * 8;
    const int chS1 = ((4 + quad) ^ (l16 & 7)) * 8;

    bf16x8 aLo[3][2], aHi[3][2], bFb[2][3][2];
    f32x4 acc[6][3] = {};

#define LDAf(buf, mh, dst)                                                    \
    {                                                                         \
      const __bf16* baseA_ = S + (buf)*24576 + (wr*96 + (mh)*48 + l16) * 64;  \
      _Pragma("unroll") for (int m_ = 0; m_ < 3; ++m_) {                      \
        dst[m_][0] = *(const bf16x8*)(baseA_ + m_*1024 + chS0);               \
        dst[m_][1] = *(const bf16x8*)(baseA_ + m_*1024 + chS1);               \
      }                                                                       \
    }
#define LDBf(buf, dst)                                                        \
    {                                                                         \
      const __bf16* baseB_ = S + (buf)*24576 + 12288 + (wn*48 + l16) * 64;    \
      _Pragma("unroll") for (int n_ = 0; n_ < 3; ++n_) {                      \
        dst[n_][0] = *(const bf16x8*)(baseB_ + n_*1024 + chS0);               \
        dst[n_][1] = *(const bf16x8*)(baseB_ + n_*1024 + chS1);               \
      }                                                                       \
    }
#define MMAC(mh, aA, bA)                                                      \
    _Pragma("unroll") for (int m_ = 0; m_ < 3; ++m_)                          \
    _Pragma("unroll") for (int n_ = 0; n_ < 3; ++n_) {                        \
      acc[(mh)*3+m_][n_] = __builtin_amdgcn_mfma_f32_16x16x32_bf16(           \
          aA[m_][0], bA[n_][0], acc[(mh)*3+m_][n_], 0, 0, 0);                 \
      acc[(mh)*3+m_][n_] = __builtin_amdgcn_mfma_f32_16x16x32_bf16(           \
          aA[m_][1], bA[n_][1], acc[(mh)*3+m_][n_], 0, 0, 0);                 \
    }
#define STAGE6(buf, k0)                                                       \
    stage_unit(A,  m0,      (k0), (buf)*3072 + 0);                            \
    stage_unit(A,  m0+64,   (k0), (buf)*3072 + 512);                          \
    stage_unit(A,  m0+128,  (k0), (buf)*3072 + 1024);                         \
    stage_unit(Bt, n0,      (k0), (buf)*3072 + 1536);                         \
    stage_unit(Bt, n0+64,   (k0), (buf)*3072 + 2048);                         \
    stage_unit(Bt, n0+128,  (k0), (buf)*3072 + 2560);

#define TILE(p, kt2)                                                          \
    LDAf(p, 1, aHi);                                                          \
    __builtin_amdgcn_s_setprio(1); MMAC(0, aLo, bFb[p]);                      \
    __builtin_amdgcn_s_setprio(0);                                            \
    LGKM0(); SB0();                                                           \
    BARR();                                                                   \
    STAGE6(p, kt2);                                                           \
    VMC(6); SB0();                                                            \
    BARR();                                                                   \
    LDAf(p^1, 0, aLo); LDBf(p^1, bFb[p^1]);                                   \
    __builtin_amdgcn_s_setprio(1); MMAC(1, aHi, bFb[p]);                      \
    __builtin_amdgcn_s_setprio(0);

    // ---- prologue: stage tiles 0,1; load tile 0's set0 fragments ----
    STAGE6(0, 0);
    STAGE6(1, 64);
    VMC(6); SB0();     // tile 0's 6 units done; tile 1's stay in flight
    BARR();
    LDAf(0, 0, aLo); LDBf(0, bFb[0]);

    // ---- main loop: K-tiles 0..17 (9 iters x 2 tiles), staging 2..19 ----
    for (int i = 0; i < 9; ++i) {
        const int kt2 = i * 128 + 128;   // k0 of tile 2i+2
        TILE(0, kt2)
        TILE(1, kt2 + 64)
    }

    // ---- epilogue: tiles 18 (buf0) and 19 (buf1), no staging ----
    LDAf(0, 1, aHi);
    __builtin_amdgcn_s_setprio(1); MMAC(0, aLo, bFb[0]);
    __builtin_amdgcn_s_setprio(0);
    LGKM0(); SB0();
    VMC(0); SB0();                     // tile 19's units (issued i=8) done
    BARR();
    LDAf(1, 0, aLo); LDBf(1, bFb[1]);
    __builtin_amdgcn_s_setprio(1); MMAC(1, aHi, bFb[0]);
    __builtin_amdgcn_s_setprio(0);
    // tile 19
    LDAf(1, 1, aHi);
    __builtin_amdgcn_s_setprio(1); MMAC(0, aLo, bFb[1]);
    __builtin_amdgcn_s_setprio(0);
    __builtin_amdgcn_s_setprio(1); MMAC(1, aHi, bFb[1]);
    __builtin_amdgcn_s_setprio(0);

    // ---- C write: row = m0+wr*96+m*16+quad*4+r, col = n0+wn*48+n*16+l16 ----
#pragma unroll
    for (int n_ = 0; n_ < 3; ++n_) {
        const int col = n0 + wn * 48 + n_ * 16 + l16;
        const float bb = bias[col];
#pragma unroll
        for (int m_ = 0; m_ < 6; ++m_) {
            const int row = m0 + wr * 96 + m_ * 16 + quad * 4;
#pragma unroll
            for (int r = 0; r < 4; ++r)
                out[(size_t)(row + r) * QKV_N + col] = (__bf16)(acc[m_][n_][r] + bb);
        }
    }

#undef LDAf
#undef LDBf
#undef MMAC
#undef STAGE6
#undef TILE
}

// ---------------------------------------------------------------------------
// Overlapped pipeline for the Wo projection: out[2304,1280] (fp32) =
// A[2304,1280] @ Bt[1280,1280]^T + bias.  BM=192, BN=64, BK=64, 4 waves
// (2M x 2N, per-wave 96x32), 64 KiB LDS -> 2 blocks/CU (cross-block
// overlap), grid 20x12 = 240 blocks, XCD-swizzled. Same schedule as
// gemm192_kernel; 8 stage units/tile -> counted vmcnt(8).
// ---------------------------------------------------------------------------
__global__ __launch_bounds__(256, 2) void gemm_wo_kernel(
    const __bf16* __restrict__ A,    // [2304,1280]
    const __bf16* __restrict__ Bt,   // [1280,1280]
    const float* __restrict__ bias,  // [1280]
    float* __restrict__ out)         // [2304,1280]
{
    // 2 bufs x (A 192x64 + B 64x64) bf16 = 64 KiB
    __shared__ __align__(16) __bf16 S[32768];

    const int tid  = threadIdx.x;
    const int wave = tid >> 6, lane = tid & 63;
    const int quad = lane >> 4, l16 = lane & 15;
    const int wr = wave >> 1, wn = wave & 1;

    const int lin = blockIdx.y * 20 + blockIdx.x;
    const int swz = (lin & 7) * 30 + (lin >> 3);
    const int m0 = (swz % 12) * 192;
    const int n0 = (swz / 12) * 64;

    // staging: 256 threads -> 32 rows/unit, 8 chunks/row
    const int rloc = tid >> 3;
    const int kcol = ((tid & 7) ^ (rloc & 7)) * 8;

    auto stage_unit = [&](const __bf16* g, int grow, int k0, int chunk0) {
        async_copy16(g + (size_t)(grow + rloc) * 1280 + (k0 + kcol),
                     S + (chunk0 + tid) * 8);
    };

    const int chS0 = ((quad) ^ (l16 & 7)) * 8;
    const int chS1 = ((4 + quad) ^ (l16 & 7)) * 8;

    bf16x8 aLo[3][2], aHi[3][2], bFb[2][2][2];
    f32x4 acc[6][2] = {};

#define LDAf2(buf, mh, dst)                                                   \
    {                                                                         \
      const __bf16* baseA_ = S + (buf)*16384 + (wr*96 + (mh)*48 + l16) * 64;  \
      _Pragma("unroll") for (int m_ = 0; m_ < 3; ++m_) {                      \
        dst[m_][0] = *(const bf16x8*)(baseA_ + m_*1024 + chS0);               \
        dst[m_][1] = *(const bf16x8*)(baseA_ + m_*1024 + chS1);               \
      }                                                                       \
    }
#define LDBf2(buf, dst)                                                       \
    {                                                                         \
      const __bf16* baseB_ = S + (buf)*16384 + 12288 + (wn*32 + l16) * 64;    \
      _Pragma("unroll") for (int n_ = 0; n_ < 2; ++n_) {                      \
        dst[n_][0] = *(const bf16x8*)(baseB_ + n_*1024 + chS0);               \
        dst[n_][1] = *(const bf16x8*)(baseB_ + n_*1024 + chS1);               \
      }                                                                       \
    }
#define MMAC2(mh, aA, bA)                                                     \
    _Pragma("unroll") for (int m_ = 0; m_ < 3; ++m_)                          \
    _Pragma("unroll") for (int n_ = 0; n_ < 2; ++n_) {                        \
      acc[(mh)*3+m_][n_] = __builtin_amdgcn_mfma_f32_16x16x32_bf16(           \
          aA[m_][0], bA[n_][0], acc[(mh)*3+m_][n_], 0, 0, 0);                 \
      acc[(mh)*3+m_][n_] = __builtin_amdgcn_mfma_f32_16x16x32_bf16(           \
          aA[m_][1], bA[n_][1], acc[(mh)*3+m_][n_], 0, 0, 0);                 \
    }
#define STAGE8(buf, k0)                                                       \
    stage_unit(A,  m0,      (k0), (buf)*2048 + 0);                            \
    stage_unit(A,  m0+32,   (k0), (buf)*2048 + 256);                          \
    stage_unit(A,  m0+64,   (k0), (buf)*2048 + 512);                          \
    stage_unit(A,  m0+96,   (k0), (buf)*2048 + 768);                          \
    stage_unit(A,  m0+128,  (k0), (buf)*2048 + 1024);                         \
    stage_unit(A,  m0+160,  (k0), (buf)*2048 + 1280);                         \
    stage_unit(Bt, n0,      (k0), (buf)*2048 + 1536);                         \
    stage_unit(Bt, n0+32,   (k0), (buf)*2048 + 1792);

#define TILE2(p, kt2)                                                         \
    LDAf2(p, 1, aHi);                                                         \
    __builtin_amdgcn_s_setprio(1); MMAC2(0, aLo, bFb[p]);                     \
    __builtin_amdgcn_s_setprio(0);                                            \
    LGKM0(); SB0();                                                           \
    BARR();                                                                   \
    STAGE8(p, kt2);                                                           \
    VMC(8); SB0();                                                            \
    BARR();                                                                   \
    LDAf2(p^1, 0, aLo); LDBf2(p^1, bFb[p^1]);                                 \
    __builtin_amdgcn_s_setprio(1); MMAC2(1, aHi, bFb[p]);                     \
    __builtin_amdgcn_s_setprio(0);

    // ---- prologue ----
    STAGE8(0, 0);
    STAGE8(1, 64);
    VMC(8); SB0();
    BARR();
    LDAf2(0, 0, aLo); LDBf2(0, bFb[0]);

    // ---- main loop: K-tiles 0..17, staging 2..19 ----
    for (int i = 0; i < 9; ++i) {
        const int kt2 = i * 128 + 128;
        TILE2(0, kt2)
        TILE2(1, kt2 + 64)
    }

    // ---- epilogue: tiles 18 (buf0), 19 (buf1) ----
    LDAf2(0, 1, aHi);
    __builtin_amdgcn_s_setprio(1); MMAC2(0, aLo, bFb[0]);
    __builtin_amdgcn_s_setprio(0);
    LGKM0(); SB0();
    VMC(0); SB0();
    BARR();
    LDAf2(1, 0, aLo); LDBf2(1, bFb[1]);
    __builtin_amdgcn_s_setprio(1); MMAC2(1, aHi, bFb[0]);
    __builtin_amdgcn_s_setprio(0);
    LDAf2(1, 1, aHi);
    __builtin_amdgcn_s_setprio(1); MMAC2(0, aLo, bFb[1]);
    __builtin_amdgcn_s_setprio(0);
    __builtin_amdgcn_s_setprio(1); MMAC2(1, aHi, bFb[1]);
    __builtin_amdgcn_s_setprio(0);

    // ---- C write ----
#pragma unroll
    for (int n_ = 0; n_ < 2; ++n_) {
        const int col = n0 + wn * 32 + n_ * 16 + l16;
        const float bb = bias[col];
#pragma unroll
        for (int m_ = 0; m_ < 6; ++m_) {
            const int row = m0 + wr * 96 + m_ * 16 + quad * 4;
#pragma unroll
            for (int r = 0; r < 4; ++r)
                out[(size_t)(row + r) * HID + col] = acc[m_][n_][r] + bb;
        }
    }

#undef LDAf2
#undef LDBf2
#undef MMAC2
#undef STAGE8
#undef TILE2
}

// ---------------------------------------------------------------------------
// Fused rotary + windowed attention. One block per (window, head).
// ---------------------------------------------------------------------------
__global__ __launch_bounds__(256) void attn_win_kernel(
    const __bf16* __restrict__ qkv,   // [2304, 3840]
    const float* __restrict__ rope,   // [2304, 40]
    __bf16* __restrict__ attn_out)    // [2304, 1280]
{
    const int w = blockIdx.x;
    const int h = blockIdx.y;

    __shared__ __bf16 Qs[64 * 104];  // [t][d], d padded 80->96, stride 104
    __shared__ __bf16 Ks[64 * 104];
    __shared__ __bf16 Vt[80 * 72];   // [d][t], stride 72
    __shared__ __bf16 Ps[64 * 72];   // probs, stride 72

    const int tid = threadIdx.x;

    for (int u = tid; u < 320; u += 256) {
        const int t = u & 63;
        const int p = u >> 6;
        const int tg = w * 64 + t;
        const size_t base = (size_t)tg * QKV_N + h * HD;
        const int d0 = p * 8;

        bf16x8 qa = *(const bf16x8*)(qkv + base + d0);
        bf16x8 qb = *(const bf16x8*)(qkv + base + d0 + 40);
        bf16x8 ka = *(const bf16x8*)(qkv + base + HID + d0);
        bf16x8 kb = *(const bf16x8*)(qkv + base + HID + d0 + 40);
        bf16x8 va = *(const bf16x8*)(qkv + base + 2 * HID + d0);
        bf16x8 vb = *(const bf16x8*)(qkv + base + 2 * HID + d0 + 40);
        float4 r0 = *(const float4*)(rope + tg * 40 + d0);
        float4 r1 = *(const float4*)(rope + tg * 40 + d0 + 4);
        const float ang[8] = {r0.x, r0.y, r0.z, r0.w, r1.x, r1.y, r1.z, r1.w};

        bf16x8 qoa, qob, koa, kob;
#pragma unroll
        for (int j = 0; j < 8; ++j) {
            float sn, cs;
            __sincosf(ang[j], &sn, &cs);
            const float q0 = (float)qa[j], q1 = (float)qb[j];
            const float k0 = (float)ka[j], k1 = (float)kb[j];
            qoa[j] = (__bf16)(q0 * cs - q1 * sn);
            qob[j] = (__bf16)(q0 * sn + q1 * cs);
            koa[j] = (__bf16)(k0 * cs - k1 * sn);
            kob[j] = (__bf16)(k0 * sn + k1 * cs);
        }
        *(bf16x8*)(Qs + t * 104 + d0)      = qoa;
        *(bf16x8*)(Qs + t * 104 + d0 + 40) = qob;
        *(bf16x8*)(Ks + t * 104 + d0)      = koa;
        *(bf16x8*)(Ks + t * 104 + d0 + 40) = kob;
#pragma unroll
        for (int j = 0; j < 8; ++j) {
            Vt[(d0 + j) * 72 + t]      = va[j];
            Vt[(d0 + j + 40) * 72 + t] = vb[j];
        }
    }
    for (int idx = tid; idx < 64 * 16; idx += 256) {
        const int t = idx >> 4, d = 80 + (idx & 15);
        Qs[t * 104 + d] = (__bf16)0.f;
        Ks[t * 104 + d] = (__bf16)0.f;
    }
    __syncthreads();

    const int wave = tid >> 6, lane = tid & 63;
    const int quad = lane >> 4, l16 = lane & 15;

    // ---- S = Q K^T ----
    f32x4 sacc[4] = {};
#pragma unroll
    for (int k0 = 0; k0 < 96; k0 += 32) {
        bf16x8 af = *(const bf16x8*)(Qs + (wave * 16 + l16) * 104 + k0 + quad * 8);
#pragma unroll
        for (int ct = 0; ct < 4; ++ct) {
            bf16x8 bf = *(const bf16x8*)(Ks + (ct * 16 + l16) * 104 + k0 + quad * 8);
            sacc[ct] = __builtin_amdgcn_mfma_f32_16x16x32_bf16(af, bf, sacc[ct], 0, 0, 0);
        }
    }

    // ---- in-register softmax over the 16-lane row group ----
    const float scale = 0.11180339887498948f;  // 1/sqrt(80)
#pragma unroll
    for (int r = 0; r < 4; ++r) {
        float m = -1e30f;
#pragma unroll
        for (int ct = 0; ct < 4; ++ct) {
            sacc[ct][r] *= scale;
            m = fmaxf(m, sacc[ct][r]);
        }
        m = fmaxf(m, __shfl_xor(m, 1));
        m = fmaxf(m, __shfl_xor(m, 2));
        m = fmaxf(m, __shfl_xor(m, 4));
        m = fmaxf(m, __shfl_xor(m, 8));
        float e[4], s = 0.f;
#pragma unroll
        for (int ct = 0; ct < 4; ++ct) {
            e[ct] = __expf(sacc[ct][r] - m);
            s += e[ct];
        }
        s += __shfl_xor(s, 1);
        s += __shfl_xor(s, 2);
        s += __shfl_xor(s, 4);
        s += __shfl_xor(s, 8);
        const float inv = 1.0f / s;
        const int row = wave * 16 + quad * 4 + r;
#pragma unroll
        for (int ct = 0; ct < 4; ++ct)
            Ps[row * 72 + ct * 16 + l16] = (__bf16)(e[ct] * inv);
    }
    __syncthreads();

    // ---- O = P V ----
    f32x4 oacc[5] = {};
#pragma unroll
    for (int k0 = 0; k0 < 64; k0 += 32) {
        bf16x8 af = *(const bf16x8*)(Ps + (wave * 16 + l16) * 72 + k0 + quad * 8);
#pragma unroll
        for (int nt = 0; nt < 5; ++nt) {
            bf16x8 bf = *(const bf16x8*)(Vt + (nt * 16 + l16) * 72 + k0 + quad * 8);
            oacc[nt] = __builtin_amdgcn_mfma_f32_16x16x32_bf16(af, bf, oacc[nt], 0, 0, 0);
        }
    }
#pragma unroll
    for (int nt = 0; nt < 5; ++nt) {
        const int d = nt * 16 + l16;
#pragma unroll
        for (int r = 0; r < 4; ++r) {
            const int t = w * 64 + wave * 16 + quad * 4 + r;
            attn_out[(size_t)t * HID + h * HD + d] = (__bf16)oacc[nt][r];
        }
    }
}

// ---------------------------------------------------------------------------
extern "C" void kernel_launch(void* const* d_in, const int* in_sizes, int n_in,
                              void* d_out, int out_size, void* d_ws, size_t ws_size,
                              hipStream_t stream) {
    const float* x    = (const float*)d_in[0];
    const float* rope = (const float*)d_in[1];
    // d_in[2] = cu_window_seqlens (statically: 36 full 64-token windows)
    const float* Wqkv = (const float*)d_in[3];
    const float* bqkv = (const float*)d_in[4];
    const float* Wo   = (const float*)d_in[5];
    const float* bo   = (const float*)d_in[6];
    float* out = (float*)d_out;

    char* ws = (char*)d_ws;
    const size_t szXb = (size_t)T_TOK * HID * 2;
    const size_t szWq = (size_t)QKV_N * HID * 2;
    const size_t szWo = (size_t)HID * HID * 2;
    __bf16* Xb      = (__bf16*)ws;
    __bf16* Wqkv_t  = (__bf16*)(ws + szXb);
    __bf16* Wo_t    = (__bf16*)(ws + szXb + szWq);
    __bf16* qkv_bf  = (__bf16*)(ws + szXb + szWq + szWo);
    __bf16* attn_bf = (__bf16*)ws;   // aliases Xb (dead after gemm_qkv)

    prep_kernel<<<NB_CONV + NB_WQKV + NB_WO, 256, 0, stream>>>(
        x, Xb, Wqkv, Wqkv_t, Wo, Wo_t);

    // 192x192x64 fragment-double-buffered pipeline: 240 blocks
    gemm192_kernel<<<dim3(QKV_N / 192, T_TOK / 192), 512, 0, stream>>>(
        Xb, Wqkv_t, bqkv, qkv_bf);

    attn_win_kernel<<<dim3(NWIN, NH), 256, 0, stream>>>(qkv_bf, rope, attn_bf);

    // 192x64x64 fragment-double-buffered pipeline: 240 blocks, 2 blk/CU
    gemm_wo_kernel<<<dim3(HID / 64, T_TOK / 192), 256, 0, stream>>>(
        attn_bf, Wo_t, bo, out);
}